// Round 5
// baseline (512.783 us; speedup 1.0000x reference)
//
#include <hip/hip_runtime.h>
#include <hip/hip_bf16.h>

using bf16 = __hip_bfloat16;
typedef __attribute__((ext_vector_type(8))) short short8;
typedef __attribute__((ext_vector_type(4))) float floatx4;

#define NB 4
#define NSEQ 4096
#define DIM 1024
#define INNER 512
#define TOK (NB * NSEQ)   // 16384

#define MODE_BF16 0
#define MODE_F32  1

// ---------------------------------------------------------------------------
// Dtype probe: read first 8192 elements of x AS bf16, count non-finite.
// True bf16 N(0,1) data -> 0. fp32 data read as bf16 -> ~16 (exp bits random).
// ---------------------------------------------------------------------------
__global__ void probe_dtype(const unsigned short* __restrict__ x, int* __restrict__ flag) {
  int cnt = 0;
  for (int i = threadIdx.x; i < 8192; i += 64)
    cnt += (((x[i] >> 7) & 0xFF) == 0xFF);
#pragma unroll
  for (int m = 32; m; m >>= 1) cnt += __shfl_down(cnt, m, 64);
  if (threadIdx.x == 0) *flag = (cnt > 0) ? MODE_F32 : MODE_BF16;
}

// ---------------------------------------------------------------------------
// staging helpers: load 8 source elems -> 8 bf16 into LDS (one 16B write)
// ---------------------------------------------------------------------------
__device__ inline void stage8(const bf16* __restrict__ src, bf16* dst) {
  *(uint4*)dst = *(const uint4*)src;
}
__device__ inline void stage8(const float* __restrict__ src, bf16* dst) {
  const float4 a = ((const float4*)src)[0];
  const float4 b = ((const float4*)src)[1];
  union { uint4 u; bf16 h[8]; } p;
  p.h[0] = __float2bfloat16(a.x); p.h[1] = __float2bfloat16(a.y);
  p.h[2] = __float2bfloat16(a.z); p.h[3] = __float2bfloat16(a.w);
  p.h[4] = __float2bfloat16(b.x); p.h[5] = __float2bfloat16(b.y);
  p.h[6] = __float2bfloat16(b.z); p.h[7] = __float2bfloat16(b.w);
  *(uint4*)dst = p.u;
}
__device__ inline float tofloat(bf16 v)  { return __bfloat162float(v); }
__device__ inline float tofloat(float v) { return v; }

// ---------------------------------------------------------------------------
// GEMM: C[M,n-tile] = A[M,K](lda) @ W[N,K]^T (+bias). bf16 MFMA, fp32 accum.
// 128x128 tile, BK=64, 4 waves, 4x4 mfma_f32_16x16x32_bf16 per wave.
// wbatch!=0: W advances by wbatch elems per 32 y-blocks (4096 rows) of A.
// ---------------------------------------------------------------------------
template <typename TA, typename TW, typename TO, bool BIAS>
__global__ __launch_bounds__(256, 2)
void gemm_bt(int mymode, const int* __restrict__ flag,
             const TA* __restrict__ A, int lda,
             const TW* __restrict__ W, size_t wbatch,
             const TW* __restrict__ bias,
             TO* __restrict__ C, int ldc, int K) {
  if (*flag != mymode) return;

  __shared__ __align__(16) bf16 As[128 * 72];
  __shared__ __align__(16) bf16 Bs[128 * 72];

  const int tid  = threadIdx.x;
  const int m0   = blockIdx.y * 128;
  const int n0   = blockIdx.x * 128;
  if (wbatch) W += (size_t)(blockIdx.y >> 5) * wbatch;

  const int wave = tid >> 6;
  const int lane = tid & 63;
  const int wr   = (wave >> 1) * 64;
  const int wc   = (wave & 1) * 64;
  const int quad = lane >> 4;
  const int r16  = lane & 15;

  floatx4 acc[4][4];
#pragma unroll
  for (int i = 0; i < 4; ++i)
#pragma unroll
    for (int j = 0; j < 4; ++j) acc[i][j] = (floatx4)0.0f;

  const int ksteps = K >> 6;
  for (int kt = 0; kt < ksteps; ++kt) {
    const int k0 = kt << 6;
#pragma unroll
    for (int l = 0; l < 4; ++l) {
      const int s   = l * 256 + tid;
      const int row = s >> 3, sub = s & 7;
      stage8(A + (size_t)(m0 + row) * lda + k0 + sub * 8, As + row * 72 + sub * 8);
      stage8(W + (size_t)(n0 + row) * K   + k0 + sub * 8, Bs + row * 72 + sub * 8);
    }
    __syncthreads();
#pragma unroll
    for (int kk = 0; kk < 64; kk += 32) {
      short8 af[4], bfg[4];
#pragma unroll
      for (int i = 0; i < 4; ++i)
        af[i] = *(const short8*)(As + (wr + i * 16 + r16) * 72 + kk + quad * 8);
#pragma unroll
      for (int j = 0; j < 4; ++j)
        bfg[j] = *(const short8*)(Bs + (wc + j * 16 + r16) * 72 + kk + quad * 8);
#pragma unroll
      for (int i = 0; i < 4; ++i)
#pragma unroll
        for (int j = 0; j < 4; ++j)
          acc[i][j] = __builtin_amdgcn_mfma_f32_16x16x32_bf16(af[i], bfg[j], acc[i][j], 0, 0, 0);
    }
    __syncthreads();
  }

  // D mapping (verified m89/m91): row = quad*4 + reg, col = lane&15
#pragma unroll
  for (int j = 0; j < 4; ++j) {
    const int col = n0 + wc + j * 16 + r16;
    const float bv = BIAS ? tofloat(bias[col]) : 0.0f;
#pragma unroll
    for (int i = 0; i < 4; ++i) {
      const int rowb = m0 + wr + i * 16 + quad * 4;
#pragma unroll
      for (int r = 0; r < 4; ++r) {
        const float v = acc[i][j][r] + bv;
        if constexpr (sizeof(TO) == 2)
          C[(size_t)(rowb + r) * ldc + col] = __float2bfloat16(v);
        else
          C[(size_t)(rowb + r) * ldc + col] = v;
      }
    }
  }
}

// ---------------------------------------------------------------------------
__global__ void zero_ctx(int mymode, const int* __restrict__ flag, float* __restrict__ ctx) {
  if (*flag != mymode) return;
  ((float4*)ctx)[blockIdx.x * 256 + threadIdx.x] = make_float4(0.f, 0.f, 0.f, 0.f);
}

__global__ void copy_w2b(int mymode, const int* __restrict__ flag,
                         const bf16* __restrict__ src, bf16* __restrict__ dst) {
  if (*flag != mymode) return;
  const int i = blockIdx.x * 256 + threadIdx.x;
  ((uint4*)dst)[i] = ((const uint4*)src)[i];
}

// ---------------------------------------------------------------------------
// softmax(k over dh=64) then ctx[bh][d][e] += sum_n sk[n,d]*v[n,e].
// kv: bf16 [16384][1024] (k cols 0..511, v cols 512..1023). ctx: fp32 [32][4096].
// ---------------------------------------------------------------------------
__global__ __launch_bounds__(256)
void softmax_context(int mymode, const int* __restrict__ flag,
                     const bf16* __restrict__ kv, float* __restrict__ ctx) {
  if (*flag != mymode) return;

  __shared__ float sk_lds[4][64];
  __shared__ float ctx_lds[64][64];

  const int tid   = threadIdx.x;
  const int wave  = tid >> 6;
  const int lane  = tid & 63;
  const int bh    = blockIdx.x >> 4;
  const int slice = blockIdx.x & 15;
  const int b     = bh >> 3, h = bh & 7;

  for (int i = tid; i < 4096; i += 256) ((float*)ctx_lds)[i] = 0.0f;
  __syncthreads();

  float col[64];
#pragma unroll
  for (int d = 0; d < 64; ++d) col[d] = 0.0f;

  for (int it = 0; it < 64; ++it) {
    const int n = slice * 256 + wave + it * 4;
    const size_t rb = (size_t)(b * NSEQ + n) * 1024;
    const float kf = __bfloat162float(kv[rb + h * 64 + lane]);
    const float vf = __bfloat162float(kv[rb + 512 + h * 64 + lane]);

    float mx = kf;
#pragma unroll
    for (int m = 32; m; m >>= 1) mx = fmaxf(mx, __shfl_xor(mx, m, 64));
    const float e = __expf(kf - mx);
    float s = e;
#pragma unroll
    for (int m = 32; m; m >>= 1) s += __shfl_xor(s, m, 64);

    __syncthreads();
    sk_lds[wave][lane] = e / s;
    __syncthreads();

#pragma unroll
    for (int d4 = 0; d4 < 16; ++d4) {
      const float4 s4 = *(const float4*)&sk_lds[wave][d4 * 4];
      col[d4 * 4 + 0] += s4.x * vf;
      col[d4 * 4 + 1] += s4.y * vf;
      col[d4 * 4 + 2] += s4.z * vf;
      col[d4 * 4 + 3] += s4.w * vf;
    }
  }

  for (int w = 0; w < 4; ++w) {
    if (wave == w) {
#pragma unroll
      for (int d = 0; d < 64; ++d) ctx_lds[d][lane] += col[d];
    }
    __syncthreads();
  }
  float* cg = ctx + (size_t)bh * 4096;
  for (int i = 0; i < 16; ++i) {
    const int idx = tid * 16 + i;
    atomicAdd(&cg[idx], ((const float*)ctx_lds)[idx]);
  }
}

// ---------------------------------------------------------------------------
// bf16-mode only: wqT[c][c'] = wq[c'][c]
// ---------------------------------------------------------------------------
__global__ __launch_bounds__(256)
void transpose_wq(int mymode, const int* __restrict__ flag,
                  const bf16* __restrict__ wq, bf16* __restrict__ wqT) {
  if (*flag != mymode) return;
  __shared__ bf16 t[64 * 72];
  const int tid = threadIdx.x;
  const int c0  = blockIdx.x * 64;
  const int r0  = blockIdx.y * 64;

#pragma unroll
  for (int i = 0; i < 2; ++i) {
    const int s = i * 256 + tid;
    const int r = s >> 3, sub = s & 7;
    *(uint4*)(t + r * 72 + sub * 8) =
        *(const uint4*)(wq + (size_t)(r0 + r) * 1024 + c0 + sub * 8);
  }
  __syncthreads();
#pragma unroll
  for (int i = 0; i < 16; ++i) {
    const int idx = i * 256 + tid;
    const int cc = idx >> 6, rr = idx & 63;
    wqT[(size_t)(c0 + cc) * 512 + r0 + rr] = t[rr * 72 + cc];
  }
}

// ---------------------------------------------------------------------------
// bf16-mode only: M2[b*1024+o][h*64+d] = sum_e w_out[o][h*64+e] * ctx[b,h][d][e]
// ---------------------------------------------------------------------------
__global__ __launch_bounds__(256)
void build_m2(int mymode, const int* __restrict__ flag,
              const bf16* __restrict__ w_out, const float* __restrict__ ctx,
              bf16* __restrict__ M2) {
  if (*flag != mymode) return;
  __shared__ __align__(16) bf16 wo_s[128 * 72];
  __shared__ __align__(16) float ctx_s[4096];

  const int tid = threadIdx.x;
  const int bh  = blockIdx.y;
  const int b   = bh >> 3, h = bh & 7;
  const int o0  = blockIdx.x * 128;

#pragma unroll
  for (int l = 0; l < 4; ++l) {
    const int s = l * 256 + tid;
    const int row = s >> 3, sub = s & 7;
    *(uint4*)(wo_s + row * 72 + sub * 8) =
        *(const uint4*)(w_out + (size_t)(o0 + row) * 512 + h * 64 + sub * 8);
  }
  const float4* cg = (const float4*)(ctx + (size_t)bh * 4096);
#pragma unroll
  for (int l = 0; l < 4; ++l) ((float4*)ctx_s)[l * 256 + tid] = cg[l * 256 + tid];
  __syncthreads();

  const int o_loc = tid & 127;
  const int dbase = (tid >> 7) * 32;
  float acc[32];
#pragma unroll
  for (int d = 0; d < 32; ++d) acc[d] = 0.0f;

  for (int e = 0; e < 64; ++e) {
    const float wf = __bfloat162float(wo_s[o_loc * 72 + e]);
#pragma unroll
    for (int d = 0; d < 32; ++d)
      acc[d] += wf * ctx_s[(dbase + d) * 64 + e];
  }

  __align__(16) bf16 tmp[32];
#pragma unroll
  for (int d = 0; d < 32; ++d) tmp[d] = __float2bfloat16(acc[d]);
  bf16* dst = M2 + (size_t)(b * 1024 + o0 + o_loc) * 512 + h * 64 + dbase;
#pragma unroll
  for (int i = 0; i < 4; ++i) ((uint4*)dst)[i] = ((const uint4*)tmp)[i];
}

// ---------------------------------------------------------------------------
// f32-mode only: attn[t][h*64+e] = sum_d q[t][h*64+d] * ctx[bh][d][e]
// q, attn: bf16 [16384][512]. Grid (32 n-tiles, 32 bh).
// ---------------------------------------------------------------------------
__global__ __launch_bounds__(256)
void apply_ctx(int mymode, const int* __restrict__ flag,
               const bf16* __restrict__ q, const float* __restrict__ ctx,
               bf16* __restrict__ attn) {
  if (*flag != mymode) return;
  __shared__ __align__(16) float ctx_lds[4096];
  __shared__ __align__(16) bf16 q_lds[128 * 72];

  const int tid = threadIdx.x;
  const int bh  = blockIdx.y;
  const int b   = bh >> 3, h = bh & 7;
  const int n0  = blockIdx.x * 128;

  const float4* cs = (const float4*)(ctx + (size_t)bh * 4096);
#pragma unroll
  for (int l = 0; l < 4; ++l) ((float4*)ctx_lds)[l * 256 + tid] = cs[l * 256 + tid];
#pragma unroll
  for (int l = 0; l < 4; ++l) {
    const int s   = l * 256 + tid;
    const int row = s >> 3, sub = s & 7;
    const uint4 v = *(const uint4*)(q + (size_t)(b * NSEQ + n0 + row) * INNER + h * 64 + sub * 8);
    *(uint4*)(q_lds + row * 72 + sub * 8) = v;
  }
  __syncthreads();

  const int rr   = (tid >> 2) << 1;
  const int part = tid & 3;
  float acc0[16], acc1[16];
#pragma unroll
  for (int i = 0; i < 16; ++i) { acc0[i] = 0.0f; acc1[i] = 0.0f; }

  for (int d8 = 0; d8 < 8; ++d8) {
    const uint4 qa = *(const uint4*)(q_lds + rr * 72 + d8 * 8);
    const uint4 qb = *(const uint4*)(q_lds + (rr + 1) * 72 + d8 * 8);
    const unsigned short* qsa = (const unsigned short*)&qa;
    const unsigned short* qsb = (const unsigned short*)&qb;
#pragma unroll
    for (int dd = 0; dd < 8; ++dd) {
      const int d = d8 * 8 + dd;
      const float q0 = __uint_as_float((unsigned)qsa[dd] << 16);
      const float q1 = __uint_as_float((unsigned)qsb[dd] << 16);
#pragma unroll
      for (int e4 = 0; e4 < 4; ++e4) {
        const float4 c4 = ((const float4*)ctx_lds)[d * 16 + part * 4 + e4];
        acc0[e4 * 4 + 0] += q0 * c4.x; acc0[e4 * 4 + 1] += q0 * c4.y;
        acc0[e4 * 4 + 2] += q0 * c4.z; acc0[e4 * 4 + 3] += q0 * c4.w;
        acc1[e4 * 4 + 0] += q1 * c4.x; acc1[e4 * 4 + 1] += q1 * c4.y;
        acc1[e4 * 4 + 2] += q1 * c4.z; acc1[e4 * 4 + 3] += q1 * c4.w;
      }
    }
  }

  const int t0 = b * NSEQ + n0 + rr;
  __align__(16) bf16 tmp0[16], tmp1[16];
#pragma unroll
  for (int i = 0; i < 16; ++i) { tmp0[i] = __float2bfloat16(acc0[i]); tmp1[i] = __float2bfloat16(acc1[i]); }
  bf16* dst0 = attn + (size_t)t0 * INNER + h * 64 + part * 16;
  bf16* dst1 = dst0 + INNER;
  ((uint4*)dst0)[0] = ((const uint4*)tmp0)[0];
  ((uint4*)dst0)[1] = ((const uint4*)tmp0)[1];
  ((uint4*)dst1)[0] = ((const uint4*)tmp1)[0];
  ((uint4*)dst1)[1] = ((const uint4*)tmp1)[1];
}

// ---------------------------------------------------------------------------
extern "C" void kernel_launch(void* const* d_in, const int* in_sizes, int n_in,
                              void* d_out, int out_size, void* d_ws, size_t ws_size,
                              hipStream_t stream) {
  int* flag = (int*)d_ws;   // 4 bytes only

  probe_dtype<<<1, 64, 0, stream>>>((const unsigned short*)d_in[0], flag);

  // ======================= BF16 pipeline (mode 0) ==========================
  {
    const bf16* x     = (const bf16*)d_in[0];
    bf16*       wqkvm = (bf16*)d_in[1];
    const bf16* w_qkv = (const bf16*)d_in[1];
    const bf16* w_out = (const bf16*)d_in[2];
    const bf16* b_out = (const bf16*)d_in[3];
    bf16* out = (bf16*)d_out;

    bf16*  kv    = out;
    bf16*  M2    = out;
    bf16*  W2    = out + (size_t)12582912;
    bf16*  wqT   = wqkvm + (size_t)524288;
    float* ctx   = (float*)(wqkvm + (size_t)1048576);
    bf16*  wcopy = wqkvm;

    gemm_bt<bf16, bf16, bf16, false><<<dim3(8, TOK / 128), 256, 0, stream>>>(
        MODE_BF16, flag, x, DIM, w_qkv + (size_t)INNER * DIM, 0, nullptr, kv, 1024, DIM);
    zero_ctx<<<128, 256, 0, stream>>>(MODE_BF16, flag, ctx);
    softmax_context<<<512, 256, 0, stream>>>(MODE_BF16, flag, kv, ctx);
    transpose_wq<<<dim3(16, 8), 256, 0, stream>>>(MODE_BF16, flag, w_qkv, wqT);
    build_m2<<<dim3(8, 32), 256, 0, stream>>>(MODE_BF16, flag, w_out, ctx, M2);
    gemm_bt<bf16, bf16, bf16, false><<<dim3(8, 32), 256, 0, stream>>>(
        MODE_BF16, flag, M2, 512, wqT, 0, nullptr, W2, 1024, 512);
    gemm_bt<bf16, bf16, bf16, true><<<dim3(8, 96), 256, 0, stream>>>(
        MODE_BF16, flag, x, DIM, W2, (size_t)1048576, b_out, out, DIM, DIM);
    copy_w2b<<<512, 256, 0, stream>>>(MODE_BF16, flag, W2 + (size_t)3 * 1048576, wcopy);
    gemm_bt<bf16, bf16, bf16, true><<<dim3(8, 32), 256, 0, stream>>>(
        MODE_BF16, flag, x + (size_t)12288 * DIM, DIM, wcopy, 0, b_out,
        out + (size_t)12288 * DIM, DIM, DIM);
  }

  // ======================= FP32 pipeline (mode 1) ==========================
  {
    const float* x     = (const float*)d_in[0];
    const float* w_qkv = (const float*)d_in[1];
    const float* w_out = (const float*)d_in[2];
    const float* b_out = (const float*)d_in[3];
    float* out = (float*)d_out;

    // d_out (64 MiB as fp32): kv bf16 [16384][1024] @ [0,32 MiB), q bf16 [16384][512] @ [32,48 MiB)
    bf16*  kv   = (bf16*)d_out;
    bf16*  q    = (bf16*)d_out + (size_t)16777216;
    // w_qkv fp32 buffer (6 MiB) dead after the two QKV GEMMs -> ctx fp32 @ byte 0
    float* ctx  = (float*)d_in[1];
    // x fp32 buffer (64 MiB) dead after the two QKV GEMMs -> attn bf16 @ byte 0
    bf16*  attn = (bf16*)d_in[0];

    // F1) kv = x @ w_qkv[512:1536]^T
    gemm_bt<float, float, bf16, false><<<dim3(8, TOK / 128), 256, 0, stream>>>(
        MODE_F32, flag, x, DIM, w_qkv + (size_t)INNER * DIM, 0, nullptr, kv, 1024, DIM);
    // F2) q = x @ w_qkv[0:512]^T
    gemm_bt<float, float, bf16, false><<<dim3(4, TOK / 128), 256, 0, stream>>>(
        MODE_F32, flag, x, DIM, w_qkv, 0, nullptr, q, INNER, DIM);
    // F3) ctx = softmax(k)^T v   (w_qkv buffer now dead)
    zero_ctx<<<128, 256, 0, stream>>>(MODE_F32, flag, ctx);
    softmax_context<<<512, 256, 0, stream>>>(MODE_F32, flag, kv, ctx);
    // F4) attn = q @ ctx  (x buffer now dead)
    apply_ctx<<<dim3(32, 32), 256, 0, stream>>>(MODE_F32, flag, q, ctx, attn);
    // F5) out = attn @ w_out^T + b_out  (reads only attn/w_out/b_out; writes all d_out)
    gemm_bt<bf16, float, float, true><<<dim3(8, TOK / 128), 256, 0, stream>>>(
        MODE_F32, flag, attn, INNER, w_out, 0, b_out, out, DIM, INNER);
  }
}

// Round 6
// 356.510 us; speedup vs baseline: 1.4383x; 1.4383x over previous
//
#include <hip/hip_runtime.h>
#include <hip/hip_bf16.h>

using bf16 = __hip_bfloat16;
typedef __attribute__((ext_vector_type(8))) short short8;
typedef __attribute__((ext_vector_type(4))) float floatx4;

#define NB 4
#define NSEQ 4096
#define DIM 1024
#define INNER 512
#define TOK (NB * NSEQ)   // 16384

// -------------------------- memory plan (no d_ws) ---------------------------
// d_out (64 MiB fp32):
//   kv bf16 [16384][1024] @ byte 0          (stages 1-4, dead after softmax)
//   M2 bf16 [4096][512]   @ byte 0          (stage 5 writes, 6 reads)
//   W2 bf16 [4096][1024]  @ byte 56 MiB     (stage 6 writes, 7a reads)
//   stage 7a writes out rows 0..14335  (bytes [0,56 MiB) - disjoint from W2)
//   stage 7c writes out rows 14336..16383 (reads wcopy, overwrites W2 region)
// w_qkv input buffer (6 MiB fp32, restored pristine before every launch):
//   wq fp32 rows 0..511 @ [0,2 MiB)  (live until transpose_wq)
//   wqT bf16 [1024][512] @ [2,3 MiB) (after kv GEMM consumed rows 512+)
//   ctx fp32 [32][64][64] @ [3,3.5 MiB)
//   wcopy bf16 (W2 batch 3) @ [0,2 MiB) (after transpose done)

__device__ inline unsigned short f2bf(float x) {
  union { bf16 h; unsigned short u; } c; c.h = __float2bfloat16(x); return c.u;
}
__device__ inline float bf2f(unsigned short u) {
  return __uint_as_float((unsigned)u << 16);
}

// staging helpers: 8 src elems -> 8 bf16 in LDS (16B write)
__device__ inline void stage8(const bf16* __restrict__ src, bf16* dst) {
  *(uint4*)dst = *(const uint4*)src;
}
__device__ inline void stage8(const float* __restrict__ src, bf16* dst) {
  const float4 a = ((const float4*)src)[0];
  const float4 b = ((const float4*)src)[1];
  union { uint4 u; bf16 h[8]; } p;
  p.h[0] = __float2bfloat16(a.x); p.h[1] = __float2bfloat16(a.y);
  p.h[2] = __float2bfloat16(a.z); p.h[3] = __float2bfloat16(a.w);
  p.h[4] = __float2bfloat16(b.x); p.h[5] = __float2bfloat16(b.y);
  p.h[6] = __float2bfloat16(b.z); p.h[7] = __float2bfloat16(b.w);
  *(uint4*)dst = p.u;
}
__device__ inline float tofloat(bf16 v)  { return __bfloat162float(v); }
__device__ inline float tofloat(float v) { return v; }

// ---------------------------------------------------------------------------
// GEMM: C[M,n-tile] = A[M,K](lda) @ W[N,K]^T (+bias). bf16 MFMA, fp32 accum.
// 128x128 tile, BK=64, 4 waves, 4x4 mfma_f32_16x16x32_bf16 per wave.
// ---------------------------------------------------------------------------
template <typename TA, typename TW, typename TB, typename TO, bool BIAS>
__global__ __launch_bounds__(256, 2)
void gemm_bt(const TA* __restrict__ A, int lda,
             const TW* __restrict__ W, size_t wbatch,
             const TB* __restrict__ bias,
             TO* __restrict__ C, int ldc, int K) {
  __shared__ __align__(16) bf16 As[128 * 72];
  __shared__ __align__(16) bf16 Bs[128 * 72];

  const int tid  = threadIdx.x;
  const int m0   = blockIdx.y * 128;
  const int n0   = blockIdx.x * 128;
  if (wbatch) W += (size_t)(blockIdx.y >> 5) * wbatch;

  const int wave = tid >> 6;
  const int lane = tid & 63;
  const int wr   = (wave >> 1) * 64;
  const int wc   = (wave & 1) * 64;
  const int quad = lane >> 4;
  const int r16  = lane & 15;

  floatx4 acc[4][4];
#pragma unroll
  for (int i = 0; i < 4; ++i)
#pragma unroll
    for (int j = 0; j < 4; ++j) acc[i][j] = (floatx4)0.0f;

  const int ksteps = K >> 6;
  for (int kt = 0; kt < ksteps; ++kt) {
    const int k0 = kt << 6;
#pragma unroll
    for (int l = 0; l < 4; ++l) {
      const int s   = l * 256 + tid;
      const int row = s >> 3, sub = s & 7;
      stage8(A + (size_t)(m0 + row) * lda + k0 + sub * 8, As + row * 72 + sub * 8);
      stage8(W + (size_t)(n0 + row) * K   + k0 + sub * 8, Bs + row * 72 + sub * 8);
    }
    __syncthreads();
#pragma unroll
    for (int kk = 0; kk < 64; kk += 32) {
      short8 af[4], bfg[4];
#pragma unroll
      for (int i = 0; i < 4; ++i)
        af[i] = *(const short8*)(As + (wr + i * 16 + r16) * 72 + kk + quad * 8);
#pragma unroll
      for (int j = 0; j < 4; ++j)
        bfg[j] = *(const short8*)(Bs + (wc + j * 16 + r16) * 72 + kk + quad * 8);
#pragma unroll
      for (int i = 0; i < 4; ++i)
#pragma unroll
        for (int j = 0; j < 4; ++j)
          acc[i][j] = __builtin_amdgcn_mfma_f32_16x16x32_bf16(af[i], bfg[j], acc[i][j], 0, 0, 0);
    }
    __syncthreads();
  }

  // D mapping (verified m89/m91): row = quad*4 + reg, col = lane&15
#pragma unroll
  for (int j = 0; j < 4; ++j) {
    const int col = n0 + wc + j * 16 + r16;
    const float bv = BIAS ? tofloat(bias[col]) : 0.0f;
#pragma unroll
    for (int i = 0; i < 4; ++i) {
      const int rowb = m0 + wr + i * 16 + quad * 4;
#pragma unroll
      for (int r = 0; r < 4; ++r) {
        const float v = acc[i][j][r] + bv;
        if constexpr (sizeof(TO) == 2)
          C[(size_t)(rowb + r) * ldc + col] = __float2bfloat16(v);
        else
          C[(size_t)(rowb + r) * ldc + col] = v;
      }
    }
  }
}

// ---------------------------------------------------------------------------
__global__ void zero_ctx(float* __restrict__ ctx) {
  ((float4*)ctx)[blockIdx.x * 256 + threadIdx.x] = make_float4(0.f, 0.f, 0.f, 0.f);
}

__global__ void copy_w2b(const bf16* __restrict__ src, bf16* __restrict__ dst) {
  const int i = blockIdx.x * 256 + threadIdx.x;   // 131072 uint4 = 2 MiB
  ((uint4*)dst)[i] = ((const uint4*)src)[i];
}

// ---------------------------------------------------------------------------
// softmax(k over dh=64) + ctx[bh][d][e] += sum_n sk[n,d]*v[n,e]  via MFMA.
// 512 blocks = 32 bh x 16 slices of 256 rows; 2 chunks of 128 rows each.
// Phase A: vectorized softmax, sk/v written transposed to LDS (stride 130:
//   ~4-way write conflicts = 1.58x, acceptable; b128 unaligned -> b32 reads).
// Phase B: ctx[64,64] += skT[64xK=128] @ vT-as-Bop[64xK], 16 mfma/wave/chunk.
// ---------------------------------------------------------------------------
__global__ __launch_bounds__(256)
void softmax_context(const unsigned short* __restrict__ kv, float* __restrict__ ctx) {
  __shared__ unsigned short skT[64 * 130];
  __shared__ unsigned short vT [64 * 130];

  const int tid   = threadIdx.x;
  const int wave  = tid >> 6;
  const int lane  = tid & 63;
  const int bh    = blockIdx.x >> 4;
  const int slice = blockIdx.x & 15;
  const int b     = bh >> 3, h = bh & 7;

  const int quad = lane >> 4;
  const int r16  = lane & 15;
  const int d0   = wave * 16;

  floatx4 acc[4];
#pragma unroll
  for (int j = 0; j < 4; ++j) acc[j] = (floatx4)0.0f;

  const int rgrp = tid >> 3;   // 0..31: row within 32-row pass
  const int c    = tid & 7;    // 8-elem chunk within row

  for (int ch = 0; ch < 2; ++ch) {
    // ---- Phase A: 4 passes x 32 rows = 128 rows ----
#pragma unroll
    for (int p = 0; p < 4; ++p) {
      const int r = p * 32 + rgrp;                      // chunk-local row
      const size_t rowbase =
          (size_t)(b * NSEQ + slice * 256 + ch * 128 + r) * 1024 + h * 64;
      const uint4 k8 = *(const uint4*)(kv + rowbase + c * 8);
      const uint4 v8 = *(const uint4*)(kv + rowbase + 512 + c * 8);
      const unsigned short* kb = (const unsigned short*)&k8;
      const unsigned short* vb = (const unsigned short*)&v8;

      float kf[8];
#pragma unroll
      for (int j = 0; j < 8; ++j) kf[j] = bf2f(kb[j]);
      float mx = kf[0];
#pragma unroll
      for (int j = 1; j < 8; ++j) mx = fmaxf(mx, kf[j]);
      mx = fmaxf(mx, __shfl_xor(mx, 1, 64));
      mx = fmaxf(mx, __shfl_xor(mx, 2, 64));
      mx = fmaxf(mx, __shfl_xor(mx, 4, 64));
      float e[8]; float s = 0.0f;
#pragma unroll
      for (int j = 0; j < 8; ++j) { e[j] = __expf(kf[j] - mx); s += e[j]; }
      s += __shfl_xor(s, 1, 64);
      s += __shfl_xor(s, 2, 64);
      s += __shfl_xor(s, 4, 64);
      const float inv = 1.0f / s;
#pragma unroll
      for (int j = 0; j < 8; ++j) {
        const int d = c * 8 + j;
        skT[d * 130 + r] = f2bf(e[j] * inv);
        vT [d * 130 + r] = vb[j];
      }
    }
    __syncthreads();

    // ---- Phase B: MFMA over K=128 ----
#pragma unroll
    for (int kk = 0; kk < 4; ++kk) {
      const int kof = kk * 32 + quad * 8;
      union { short8 v; unsigned u[4]; } afr;
      {
        const unsigned* q = (const unsigned*)(skT + (d0 + r16) * 130 + kof);
        afr.u[0] = q[0]; afr.u[1] = q[1]; afr.u[2] = q[2]; afr.u[3] = q[3];
      }
#pragma unroll
      for (int j = 0; j < 4; ++j) {
        union { short8 v; unsigned u[4]; } bfr;
        const unsigned* q = (const unsigned*)(vT + (j * 16 + r16) * 130 + kof);
        bfr.u[0] = q[0]; bfr.u[1] = q[1]; bfr.u[2] = q[2]; bfr.u[3] = q[3];
        acc[j] = __builtin_amdgcn_mfma_f32_16x16x32_bf16(afr.v, bfr.v, acc[j], 0, 0, 0);
      }
    }
    __syncthreads();
  }

  // D[m][n]: m = d-within-strip = quad*4+reg, n = e = j*16 + r16
  float* cg = ctx + (size_t)bh * 4096;
#pragma unroll
  for (int j = 0; j < 4; ++j) {
    const int e = j * 16 + r16;
#pragma unroll
    for (int r = 0; r < 4; ++r) {
      const int d = d0 + quad * 4 + r;
      atomicAdd(cg + d * 64 + e, acc[j][r]);
    }
  }
}

// ---------------------------------------------------------------------------
// wqT[c][c'] = bf16(wq[c'][c])   wq fp32 [512][1024]
// ---------------------------------------------------------------------------
__global__ __launch_bounds__(256)
void transpose_wq(const float* __restrict__ wq, bf16* __restrict__ wqT) {
  __shared__ unsigned short t[64 * 68];
  const int tid = threadIdx.x;
  const int c0  = blockIdx.x * 64;   // col block (0..1023)
  const int r0  = blockIdx.y * 64;   // row block (0..511)

#pragma unroll
  for (int l = 0; l < 4; ++l) {
    const int s = l * 256 + tid;            // 1024 float4
    const int row = s >> 4, col4 = s & 15;
    const float4 v = *(const float4*)(wq + (size_t)(r0 + row) * 1024 + c0 + col4 * 4);
    t[row * 68 + col4 * 4 + 0] = f2bf(v.x);
    t[row * 68 + col4 * 4 + 1] = f2bf(v.y);
    t[row * 68 + col4 * 4 + 2] = f2bf(v.z);
    t[row * 68 + col4 * 4 + 3] = f2bf(v.w);
  }
  __syncthreads();
#pragma unroll
  for (int l = 0; l < 2; ++l) {
    const int s = l * 256 + tid;            // 512 uint4 outputs
    const int cc = s >> 3, g = s & 7;
    union { uint4 u; unsigned short h[8]; } o;
#pragma unroll
    for (int u = 0; u < 8; ++u) o.h[u] = t[(g * 8 + u) * 68 + cc];
    *(uint4*)((unsigned short*)wqT + (size_t)(c0 + cc) * 512 + r0 + g * 8) = o.u;
  }
}

// ---------------------------------------------------------------------------
// M2[b*1024+o][h*64+d] = sum_e w_out[o][h*64+e] * ctx[b,h][d][e]; w_out fp32.
// ---------------------------------------------------------------------------
__global__ __launch_bounds__(256)
void build_m2(const float* __restrict__ w_out, const float* __restrict__ ctx,
              bf16* __restrict__ M2) {
  __shared__ unsigned short wo_s[128 * 68];
  __shared__ __align__(16) float ctx_s[4096];

  const int tid = threadIdx.x;
  const int bh  = blockIdx.y;
  const int b   = bh >> 3, h = bh & 7;
  const int o0  = blockIdx.x * 128;

#pragma unroll
  for (int l = 0; l < 8; ++l) {
    const int s = l * 256 + tid;            // 2048 float4 (128 rows x 16)
    const int row = s >> 4, col4 = s & 15;
    const float4 v = *(const float4*)(w_out + (size_t)(o0 + row) * 512 + h * 64 + col4 * 4);
    wo_s[row * 68 + col4 * 4 + 0] = f2bf(v.x);
    wo_s[row * 68 + col4 * 4 + 1] = f2bf(v.y);
    wo_s[row * 68 + col4 * 4 + 2] = f2bf(v.z);
    wo_s[row * 68 + col4 * 4 + 3] = f2bf(v.w);
  }
  const float4* cg = (const float4*)(ctx + (size_t)bh * 4096);
#pragma unroll
  for (int l = 0; l < 4; ++l) ((float4*)ctx_s)[l * 256 + tid] = cg[l * 256 + tid];
  __syncthreads();

  const int o_loc = tid & 127;
  const int dbase = (tid >> 7) * 32;
  float acc[32];
#pragma unroll
  for (int d = 0; d < 32; ++d) acc[d] = 0.0f;

  for (int e = 0; e < 64; ++e) {
    const float wf = bf2f(wo_s[o_loc * 68 + e]);
#pragma unroll
    for (int d = 0; d < 32; ++d)
      acc[d] += wf * ctx_s[(dbase + d) * 64 + e];
  }

  union { uint4 u[4]; unsigned short h[32]; } o;
#pragma unroll
  for (int d = 0; d < 32; ++d) o.h[d] = f2bf(acc[d]);
  unsigned short* dst = (unsigned short*)M2 + (size_t)(b * 1024 + o0 + o_loc) * 512 + h * 64 + dbase;
#pragma unroll
  for (int i = 0; i < 4; ++i) ((uint4*)dst)[i] = o.u[i];
}

// ---------------------------------------------------------------------------
extern "C" void kernel_launch(void* const* d_in, const int* in_sizes, int n_in,
                              void* d_out, int out_size, void* d_ws, size_t ws_size,
                              hipStream_t stream) {
  const float* x     = (const float*)d_in[0];
  const float* w_qkv = (const float*)d_in[1];
  const float* w_out = (const float*)d_in[2];
  const float* b_out = (const float*)d_in[3];
  float* out = (float*)d_out;

  char* wsc = (char*)d_in[1];                       // w_qkv buffer as scratch
  bf16*  wqT   = (bf16*)(wsc + 2097152);            // [2,3 MiB)
  float* ctx   = (float*)(wsc + 3145728);           // [3,3.5 MiB)
  bf16*  wcopy = (bf16*)wsc;                        // [0,2 MiB) after transpose

  bf16* kv = (bf16*)d_out;                          // [0,32 MiB)
  bf16* M2 = (bf16*)d_out;                          // [0,4 MiB) after kv dead
  bf16* W2 = (bf16*)d_out + (size_t)29360128;       // byte 56 MiB

  // 1) kv = x @ w_qkv[512:1536]^T  (k | v)  -> d_out
  gemm_bt<float, float, float, bf16, false><<<dim3(8, TOK / 128), 256, 0, stream>>>(
      x, DIM, w_qkv + (size_t)INNER * DIM, 0, nullptr, kv, 1024, DIM);

  // 2) wqT = bf16(wq^T)  (w_qkv rows 512+ now dead)
  transpose_wq<<<dim3(16, 8), 256, 0, stream>>>(w_qkv, wqT);

  // 3) ctx = softmax(k)^T v
  zero_ctx<<<128, 256, 0, stream>>>(ctx);
  softmax_context<<<512, 256, 0, stream>>>((const unsigned short*)kv, ctx);

  // 4) M2 = w_out folded through ctx  -> d_out[0,4 MiB)
  build_m2<<<dim3(8, 32), 256, 0, stream>>>(w_out, ctx, M2);

  // 5) W2[b*1024+o][c] = sum_{c'} M2[.][c'] * wqT[c][c']  -> d_out[56,64 MiB)
  gemm_bt<bf16, bf16, float, bf16, false><<<dim3(8, 32), 256, 0, stream>>>(
      M2, 512, wqT, 0, nullptr, W2, 1024, 512);

  // 6a) out rows 0..14335: writes [0,56 MiB), reads W2 [56,64) - disjoint
  gemm_bt<float, bf16, float, float, true><<<dim3(8, 112), 256, 0, stream>>>(
      x, DIM, W2, (size_t)1048576, b_out, out, DIM, DIM);

  // 6b) save W2[batch 3] into w_qkv scratch (wq fully consumed)
  copy_w2b<<<512, 256, 0, stream>>>(W2 + (size_t)3 * 1048576, wcopy);

  // 6c) out rows 14336..16383 from the copy (overwrites W2 region safely)
  gemm_bt<float, bf16, float, float, true><<<dim3(8, 16), 256, 0, stream>>>(
      x + (size_t)14336 * DIM, DIM, wcopy, 0, b_out,
      out + (size_t)14336 * DIM, DIM, DIM);
}

// Round 7
// 274.284 us; speedup vs baseline: 1.8695x; 1.2998x over previous
//
#include <hip/hip_runtime.h>
#include <hip/hip_bf16.h>

using bf16 = __hip_bfloat16;
typedef __attribute__((ext_vector_type(8))) short short8;
typedef __attribute__((ext_vector_type(4))) float floatx4;

#define NB 4
#define NSEQ 4096
#define DIM 1024
#define INNER 512
#define TOK (NB * NSEQ)   // 16384

// -------------------------- memory plan (no d_ws) ---------------------------
// d_out (64 MiB fp32):
//   xb bf16 [16384][1024] @ [0,32 MiB)   (stage 1 writes; stages 2,8 read)
//   final GEMM (9) writes all of d_out (xb relocated to xbuf first)
// x input buffer "xbuf" (64 MiB, restored pristine pre-launch; dead after stage 1):
//   kv bf16 [16384][1024] @ [0,32 MiB)   (stage 2 writes, 5 reads; then dead)
//   M2 bf16 [4096][512]   @ [32,36 MiB)
//   W2 bf16 [4096][1024]  @ [36,44 MiB)
//   xb copy               @ [0,32 MiB)   (stage 8; kv dead)
// w_qkv input buffer "wbuf" (6 MiB fp32; rows 512.. consumed by stage 2):
//   wqT bf16 [1024][512]  @ [2,3 MiB)
//   ctx fp32 [32][64][64] @ [3,3.5 MiB)

__device__ inline unsigned short f2bf(float x) {
  union { bf16 h; unsigned short u; } c; c.h = __float2bfloat16(x); return c.u;
}
__device__ inline float bf2f(unsigned short u) {
  return __uint_as_float((unsigned)u << 16);
}

// staging helpers: 8 src elems -> 8 bf16 in LDS (16B write)
__device__ inline void stage8(const bf16* __restrict__ src, bf16* dst) {
  *(uint4*)dst = *(const uint4*)src;
}
__device__ inline void stage8(const float* __restrict__ src, bf16* dst) {
  const float4 a = ((const float4*)src)[0];
  const float4 b = ((const float4*)src)[1];
  union { uint4 u; bf16 h[8]; } p;
  p.h[0] = __float2bfloat16(a.x); p.h[1] = __float2bfloat16(a.y);
  p.h[2] = __float2bfloat16(a.z); p.h[3] = __float2bfloat16(a.w);
  p.h[4] = __float2bfloat16(b.x); p.h[5] = __float2bfloat16(b.y);
  p.h[6] = __float2bfloat16(b.z); p.h[7] = __float2bfloat16(b.w);
  *(uint4*)dst = p.u;
}

// ---------------------------------------------------------------------------
// x fp32 -> xb bf16, one shot. 2M uint4 writes.
// ---------------------------------------------------------------------------
__global__ __launch_bounds__(256)
void convert_x(const float* __restrict__ x, bf16* __restrict__ xb) {
  const size_t i = (size_t)blockIdx.x * 256 + threadIdx.x;   // 8 elems each
  stage8(x + i * 8, xb + i * 8);
}

__global__ __launch_bounds__(256)
void copy16(const uint4* __restrict__ src, uint4* __restrict__ dst) {
  const size_t i = (size_t)blockIdx.x * 256 + threadIdx.x;
  dst[i] = src[i];
}

__global__ void zero_ctx(float* __restrict__ ctx) {
  ((float4*)ctx)[blockIdx.x * 256 + threadIdx.x] = make_float4(0.f, 0.f, 0.f, 0.f);
}

// ---------------------------------------------------------------------------
// GEMM: C[M,n-tile] = A[M,K](lda) @ W[N,K]^T (+bias). bf16 MFMA, fp32 accum.
// 128x128 tile, BK=64, 4 waves, 4x4 mfma_f32_16x16x32_bf16 per wave.
// launch_bounds(256,4): 4 blocks/CU (VGPR<=128, LDS 36KB*4=144<=160).
// ---------------------------------------------------------------------------
template <typename TA, typename TW, typename TO, bool BIAS>
__global__ __launch_bounds__(256, 4)
void gemm_bt(const TA* __restrict__ A, int lda,
             const TW* __restrict__ W, size_t wbatch,
             const float* __restrict__ bias,
             TO* __restrict__ C, int ldc, int K) {
  __shared__ __align__(16) bf16 As[128 * 72];
  __shared__ __align__(16) bf16 Bs[128 * 72];

  const int tid  = threadIdx.x;
  const int m0   = blockIdx.y * 128;
  const int n0   = blockIdx.x * 128;
  if (wbatch) W += (size_t)(blockIdx.y >> 5) * wbatch;

  const int wave = tid >> 6;
  const int lane = tid & 63;
  const int wr   = (wave >> 1) * 64;
  const int wc   = (wave & 1) * 64;
  const int quad = lane >> 4;
  const int r16  = lane & 15;

  floatx4 acc[4][4];
#pragma unroll
  for (int i = 0; i < 4; ++i)
#pragma unroll
    for (int j = 0; j < 4; ++j) acc[i][j] = (floatx4)0.0f;

  const int ksteps = K >> 6;
  for (int kt = 0; kt < ksteps; ++kt) {
    const int k0 = kt << 6;
#pragma unroll
    for (int l = 0; l < 4; ++l) {
      const int s   = l * 256 + tid;
      const int row = s >> 3, sub = s & 7;
      stage8(A + (size_t)(m0 + row) * lda + k0 + sub * 8, As + row * 72 + sub * 8);
      stage8(W + (size_t)(n0 + row) * K   + k0 + sub * 8, Bs + row * 72 + sub * 8);
    }
    __syncthreads();
#pragma unroll
    for (int kk = 0; kk < 64; kk += 32) {
      short8 af[4], bfg[4];
#pragma unroll
      for (int i = 0; i < 4; ++i)
        af[i] = *(const short8*)(As + (wr + i * 16 + r16) * 72 + kk + quad * 8);
#pragma unroll
      for (int j = 0; j < 4; ++j)
        bfg[j] = *(const short8*)(Bs + (wc + j * 16 + r16) * 72 + kk + quad * 8);
#pragma unroll
      for (int i = 0; i < 4; ++i)
#pragma unroll
        for (int j = 0; j < 4; ++j)
          acc[i][j] = __builtin_amdgcn_mfma_f32_16x16x32_bf16(af[i], bfg[j], acc[i][j], 0, 0, 0);
    }
    __syncthreads();
  }

  // D mapping (verified m89/m91): row = quad*4 + reg, col = lane&15
#pragma unroll
  for (int j = 0; j < 4; ++j) {
    const int col = n0 + wc + j * 16 + r16;
    const float bv = BIAS ? bias[col] : 0.0f;
#pragma unroll
    for (int i = 0; i < 4; ++i) {
      const int rowb = m0 + wr + i * 16 + quad * 4;
#pragma unroll
      for (int r = 0; r < 4; ++r) {
        const float v = acc[i][j][r] + bv;
        if constexpr (sizeof(TO) == 2)
          C[(size_t)(rowb + r) * ldc + col] = __float2bfloat16(v);
        else
          C[(size_t)(rowb + r) * ldc + col] = v;
      }
    }
  }
}

// ---------------------------------------------------------------------------
// softmax(k over dh=64) + ctx[bh][d][e] += sum_n sk[n,d]*v[n,e]  via MFMA.
// 512 blocks = 32 bh x 16 slices of 256 rows; 2 chunks of 128 rows each.
// ---------------------------------------------------------------------------
__global__ __launch_bounds__(256)
void softmax_context(const unsigned short* __restrict__ kv, float* __restrict__ ctx) {
  __shared__ unsigned short skT[64 * 130];
  __shared__ unsigned short vT [64 * 130];

  const int tid   = threadIdx.x;
  const int wave  = tid >> 6;
  const int lane  = tid & 63;
  const int bh    = blockIdx.x >> 4;
  const int slice = blockIdx.x & 15;
  const int b     = bh >> 3, h = bh & 7;

  const int quad = lane >> 4;
  const int r16  = lane & 15;
  const int d0   = wave * 16;

  floatx4 acc[4];
#pragma unroll
  for (int j = 0; j < 4; ++j) acc[j] = (floatx4)0.0f;

  const int rgrp = tid >> 3;
  const int c    = tid & 7;

  for (int ch = 0; ch < 2; ++ch) {
#pragma unroll
    for (int p = 0; p < 4; ++p) {
      const int r = p * 32 + rgrp;
      const size_t rowbase =
          (size_t)(b * NSEQ + slice * 256 + ch * 128 + r) * 1024 + h * 64;
      const uint4 k8 = *(const uint4*)(kv + rowbase + c * 8);
      const uint4 v8 = *(const uint4*)(kv + rowbase + 512 + c * 8);
      const unsigned short* kb = (const unsigned short*)&k8;
      const unsigned short* vb = (const unsigned short*)&v8;

      float kf[8];
#pragma unroll
      for (int j = 0; j < 8; ++j) kf[j] = bf2f(kb[j]);
      float mx = kf[0];
#pragma unroll
      for (int j = 1; j < 8; ++j) mx = fmaxf(mx, kf[j]);
      mx = fmaxf(mx, __shfl_xor(mx, 1, 64));
      mx = fmaxf(mx, __shfl_xor(mx, 2, 64));
      mx = fmaxf(mx, __shfl_xor(mx, 4, 64));
      float e[8]; float s = 0.0f;
#pragma unroll
      for (int j = 0; j < 8; ++j) { e[j] = __expf(kf[j] - mx); s += e[j]; }
      s += __shfl_xor(s, 1, 64);
      s += __shfl_xor(s, 2, 64);
      s += __shfl_xor(s, 4, 64);
      const float inv = 1.0f / s;
#pragma unroll
      for (int j = 0; j < 8; ++j) {
        const int d = c * 8 + j;
        skT[d * 130 + r] = f2bf(e[j] * inv);
        vT [d * 130 + r] = vb[j];
      }
    }
    __syncthreads();

#pragma unroll
    for (int kk = 0; kk < 4; ++kk) {
      const int kof = kk * 32 + quad * 8;
      union { short8 v; unsigned u[4]; } afr;
      {
        const unsigned* q = (const unsigned*)(skT + (d0 + r16) * 130 + kof);
        afr.u[0] = q[0]; afr.u[1] = q[1]; afr.u[2] = q[2]; afr.u[3] = q[3];
      }
#pragma unroll
      for (int j = 0; j < 4; ++j) {
        union { short8 v; unsigned u[4]; } bfr;
        const unsigned* q = (const unsigned*)(vT + (j * 16 + r16) * 130 + kof);
        bfr.u[0] = q[0]; bfr.u[1] = q[1]; bfr.u[2] = q[2]; bfr.u[3] = q[3];
        acc[j] = __builtin_amdgcn_mfma_f32_16x16x32_bf16(afr.v, bfr.v, acc[j], 0, 0, 0);
      }
    }
    __syncthreads();
  }

  float* cg = ctx + (size_t)bh * 4096;
#pragma unroll
  for (int j = 0; j < 4; ++j) {
    const int e = j * 16 + r16;
#pragma unroll
    for (int r = 0; r < 4; ++r) {
      const int d = d0 + quad * 4 + r;
      atomicAdd(cg + d * 64 + e, acc[j][r]);
    }
  }
}

// ---------------------------------------------------------------------------
// wqT[c][c'] = bf16(wq[c'][c])   wq fp32 [512][1024]
// ---------------------------------------------------------------------------
__global__ __launch_bounds__(256)
void transpose_wq(const float* __restrict__ wq, bf16* __restrict__ wqT) {
  __shared__ unsigned short t[64 * 68];
  const int tid = threadIdx.x;
  const int c0  = blockIdx.x * 64;
  const int r0  = blockIdx.y * 64;

#pragma unroll
  for (int l = 0; l < 4; ++l) {
    const int s = l * 256 + tid;
    const int row = s >> 4, col4 = s & 15;
    const float4 v = *(const float4*)(wq + (size_t)(r0 + row) * 1024 + c0 + col4 * 4);
    t[row * 68 + col4 * 4 + 0] = f2bf(v.x);
    t[row * 68 + col4 * 4 + 1] = f2bf(v.y);
    t[row * 68 + col4 * 4 + 2] = f2bf(v.z);
    t[row * 68 + col4 * 4 + 3] = f2bf(v.w);
  }
  __syncthreads();
#pragma unroll
  for (int l = 0; l < 2; ++l) {
    const int s = l * 256 + tid;
    const int cc = s >> 3, g = s & 7;
    union { uint4 u; unsigned short h[8]; } o;
#pragma unroll
    for (int u = 0; u < 8; ++u) o.h[u] = t[(g * 8 + u) * 68 + cc];
    *(uint4*)((unsigned short*)wqT + (size_t)(c0 + cc) * 512 + r0 + g * 8) = o.u;
  }
}

// ---------------------------------------------------------------------------
// M2[b*1024+o][h*64+d] = sum_e w_out[o][h*64+e] * ctx[b,h][d][e]; w_out fp32.
// ---------------------------------------------------------------------------
__global__ __launch_bounds__(256)
void build_m2(const float* __restrict__ w_out, const float* __restrict__ ctx,
              bf16* __restrict__ M2) {
  __shared__ unsigned short wo_s[128 * 68];
  __shared__ __align__(16) float ctx_s[4096];

  const int tid = threadIdx.x;
  const int bh  = blockIdx.y;
  const int b   = bh >> 3, h = bh & 7;
  const int o0  = blockIdx.x * 128;

#pragma unroll
  for (int l = 0; l < 8; ++l) {
    const int s = l * 256 + tid;
    const int row = s >> 4, col4 = s & 15;
    const float4 v = *(const float4*)(w_out + (size_t)(o0 + row) * 512 + h * 64 + col4 * 4);
    wo_s[row * 68 + col4 * 4 + 0] = f2bf(v.x);
    wo_s[row * 68 + col4 * 4 + 1] = f2bf(v.y);
    wo_s[row * 68 + col4 * 4 + 2] = f2bf(v.z);
    wo_s[row * 68 + col4 * 4 + 3] = f2bf(v.w);
  }
  const float4* cg = (const float4*)(ctx + (size_t)bh * 4096);
#pragma unroll
  for (int l = 0; l < 4; ++l) ((float4*)ctx_s)[l * 256 + tid] = cg[l * 256 + tid];
  __syncthreads();

  const int o_loc = tid & 127;
  const int dbase = (tid >> 7) * 32;
  float acc[32];
#pragma unroll
  for (int d = 0; d < 32; ++d) acc[d] = 0.0f;

  for (int e = 0; e < 64; ++e) {
    const float wf = bf2f(wo_s[o_loc * 68 + e]);
#pragma unroll
    for (int d = 0; d < 32; ++d)
      acc[d] += wf * ctx_s[(dbase + d) * 64 + e];
  }

  union { uint4 u[4]; unsigned short h[32]; } o;
#pragma unroll
  for (int d = 0; d < 32; ++d) o.h[d] = f2bf(acc[d]);
  unsigned short* dst = (unsigned short*)M2 + (size_t)(b * 1024 + o0 + o_loc) * 512 + h * 64 + dbase;
#pragma unroll
  for (int i = 0; i < 4; ++i) ((uint4*)dst)[i] = o.u[i];
}

// ---------------------------------------------------------------------------
extern "C" void kernel_launch(void* const* d_in, const int* in_sizes, int n_in,
                              void* d_out, int out_size, void* d_ws, size_t ws_size,
                              hipStream_t stream) {
  const float* x     = (const float*)d_in[0];
  const float* w_qkv = (const float*)d_in[1];
  const float* w_out = (const float*)d_in[2];
  const float* b_out = (const float*)d_in[3];
  float* out = (float*)d_out;

  char* xbuf = (char*)d_in[0];                      // 64 MiB scratch after stage 1
  char* wbuf = (char*)d_in[1];                      // 6 MiB

  bf16*  xb  = (bf16*)d_out;                        // [0,32 MiB) of d_out
  bf16*  kv  = (bf16*)xbuf;                         // [0,32)
  bf16*  M2  = (bf16*)(xbuf + (size_t)33554432);    // [32,36)
  bf16*  W2  = (bf16*)(xbuf + (size_t)37748736);    // [36,44)
  bf16*  xb2 = (bf16*)xbuf;                         // [0,32) after kv dead
  bf16*  wqT = (bf16*)(wbuf + 2097152);             // [2,3)
  float* ctx = (float*)(wbuf + 3145728);            // [3,3.5)

  // 1) xb = bf16(x)  (x buffer fully consumed -> becomes scratch)
  convert_x<<<8192, 256, 0, stream>>>(x, xb);

  // 2) kv = xb @ w_qkv[512:1536]^T  (fp32 W staged w/ cvt) -> xbuf[0,32)
  gemm_bt<bf16, float, bf16, false><<<dim3(8, TOK / 128), 256, 0, stream>>>(
      xb, DIM, w_qkv + (size_t)INNER * DIM, 0, nullptr, kv, 1024, DIM);

  // 3) wbuf rows 512+ now dead: ctx zero + wqT transpose
  zero_ctx<<<128, 256, 0, stream>>>(ctx);
  transpose_wq<<<dim3(16, 8), 256, 0, stream>>>(w_qkv, wqT);

  // 4) ctx = softmax(k)^T v
  softmax_context<<<512, 256, 0, stream>>>((const unsigned short*)kv, ctx);

  // 5) M2 = w_out folded through ctx
  build_m2<<<dim3(8, 32), 256, 0, stream>>>(w_out, ctx, M2);

  // 6) W2 = M2 @ wqT^T  (M=4096, N=1024, K=512)
  gemm_bt<bf16, bf16, bf16, false><<<dim3(8, 32), 256, 0, stream>>>(
      M2, 512, wqT, 0, nullptr, W2, 1024, 512);

  // 7) relocate xb -> xbuf[0,32) (kv dead)
  copy16<<<8192, 256, 0, stream>>>((const uint4*)xb, (uint4*)xb2);

  // 8) out = xb2 @ W2[b]^T + b_out  (writes all of d_out)
  gemm_bt<bf16, bf16, float, true><<<dim3(8, TOK / 128), 256, 0, stream>>>(
      xb2, DIM, W2, (size_t)1048576, b_out, out, DIM, DIM);
}

// Round 8
// 270.641 us; speedup vs baseline: 1.8947x; 1.0135x over previous
//
#include <hip/hip_runtime.h>
#include <hip/hip_bf16.h>

using bf16 = __hip_bfloat16;
typedef __attribute__((ext_vector_type(8))) short short8;
typedef __attribute__((ext_vector_type(4))) float floatx4;

#define NB 4
#define NSEQ 4096
#define DIM 1024
#define INNER 512
#define TOK (NB * NSEQ)   // 16384

// -------------------------- memory plan (no d_ws) ---------------------------
// d_out (64 MiB fp32):
//   xb bf16 [16384][1024] @ [0,32 MiB)
//   stage 8a writes d_out[32,64) (out rows 8192..16383), reads xb rows 8192+ = [16,32)
//   stage 8c writes d_out[0,32)  (out rows 0..8191), reads xb-lo copy from xbuf
// x input "xbuf" (64 MiB, dead after convert_x):
//   kv   bf16 [16384][1024] @ [0,32 MiB)   (dead after softmax)
//   M2   bf16 [4096][512]   @ [32,36 MiB)
//   W2   bf16 [4096][1024]  @ [36,44 MiB)
//   wkvb bf16 [1024][1024]  @ [48,50 MiB)
//   xb-lo copy (16 MiB)     @ [0,16 MiB)   (stage 8b, kv dead)
// w_qkv input "wbuf" (6 MiB fp32; bytes [2,6) dead after convert_wkv):
//   wqT bf16 [1024][512]  @ [2,3 MiB)
//   ctx fp32 [32][64][64] @ [3,3.5 MiB)

__device__ inline unsigned short f2bf(float x) {
  union { bf16 h; unsigned short u; } c; c.h = __float2bfloat16(x); return c.u;
}
__device__ inline float bf2f(unsigned short u) {
  return __uint_as_float((unsigned)u << 16);
}
__device__ inline void cvt8(const float* __restrict__ src, bf16* dst) {
  const float4 a = ((const float4*)src)[0];
  const float4 b = ((const float4*)src)[1];
  union { uint4 u; bf16 h[8]; } p;
  p.h[0] = __float2bfloat16(a.x); p.h[1] = __float2bfloat16(a.y);
  p.h[2] = __float2bfloat16(a.z); p.h[3] = __float2bfloat16(a.w);
  p.h[4] = __float2bfloat16(b.x); p.h[5] = __float2bfloat16(b.y);
  p.h[6] = __float2bfloat16(b.z); p.h[7] = __float2bfloat16(b.w);
  *(uint4*)dst = p.u;
}

// async global->LDS, 16 B per lane; HW writes lane i at ldsbase + i*16.
__device__ inline void gload_lds16(const bf16* g, bf16* ldsbase) {
  __builtin_amdgcn_global_load_lds(
      (const __attribute__((address_space(1))) void*)g,
      (__attribute__((address_space(3))) void*)ldsbase, 16, 0, 0);
}

// ---------------------------------------------------------------------------
__global__ __launch_bounds__(256)
void convert_x(const float* __restrict__ x, bf16* __restrict__ xb) {
  const size_t i = (size_t)blockIdx.x * 256 + threadIdx.x;
  cvt8(x + i * 8, xb + i * 8);
}

__global__ __launch_bounds__(256)
void copy16(const uint4* __restrict__ src, uint4* __restrict__ dst) {
  const size_t i = (size_t)blockIdx.x * 256 + threadIdx.x;
  dst[i] = src[i];
}

__global__ void zero_ctx(float* __restrict__ ctx) {
  ((float4*)ctx)[blockIdx.x * 256 + threadIdx.x] = make_float4(0.f, 0.f, 0.f, 0.f);
}

// ---------------------------------------------------------------------------
// GEMM: C[M tile, N tile] = A[.,K] @ W[N,K]^T (+bias). All-bf16 operands.
// 128x128 tile, BK=64, 4 waves, 4x4 mfma_f32_16x16x32_bf16.
// Staging: global_load_lds width=16 into UNPADDED 128x64 LDS tiles (m97).
// 1D grid, m_tile = p % mTiles (mTiles % 8 == 0) -> row-strip-sharing blocks
// land on the same XCD (round-robin dispatch) for L2 reuse.
// ---------------------------------------------------------------------------
template <typename TO, bool BIAS>
__global__ __launch_bounds__(256, 4)
void gemm_bt(const bf16* __restrict__ A, int lda,
             const bf16* __restrict__ W, size_t wbatch, int mTiles,
             const float* __restrict__ bias,
             TO* __restrict__ C, int ldc, int K) {
  __shared__ __align__(16) bf16 As[128 * 64];
  __shared__ __align__(16) bf16 Bs[128 * 64];

  const int tid    = threadIdx.x;
  const int p      = blockIdx.x;
  const int m_tile = p % mTiles;
  const int n_tile = p / mTiles;
  const int m0     = m_tile * 128;
  const int n0     = n_tile * 128;
  if (wbatch) W += (size_t)(m_tile >> 5) * wbatch;

  const int wave = tid >> 6;
  const int lane = tid & 63;
  const int wr   = (wave >> 1) * 64;
  const int wc   = (wave & 1) * 64;
  const int quad = lane >> 4;
  const int r16  = lane & 15;
  const int lrow = lane >> 3;   // 0..7 within a segment
  const int lcol = lane & 7;    // 16B chunk within row

  floatx4 acc[4][4];
#pragma unroll
  for (int i = 0; i < 4; ++i)
#pragma unroll
    for (int j = 0; j < 4; ++j) acc[i][j] = (floatx4)0.0f;

  const int ksteps = K >> 6;
  for (int kt = 0; kt < ksteps; ++kt) {
    const int k0 = kt << 6;
    // each wave: 4 A-segments + 4 B-segments of 8 rows x 64 cols
#pragma unroll
    for (int t = 0; t < 4; ++t) {
      const int s   = wave * 4 + t;
      const int row = s * 8 + lrow;
      gload_lds16(A + (size_t)(m0 + row) * lda + k0 + lcol * 8, As + s * 512);
      gload_lds16(W + (size_t)(n0 + row) * K   + k0 + lcol * 8, Bs + s * 512);
    }
    __syncthreads();
#pragma unroll
    for (int kk = 0; kk < 64; kk += 32) {
      short8 af[4], bfg[4];
#pragma unroll
      for (int i = 0; i < 4; ++i)
        af[i] = *(const short8*)(As + (wr + i * 16 + r16) * 64 + kk + quad * 8);
#pragma unroll
      for (int j = 0; j < 4; ++j)
        bfg[j] = *(const short8*)(Bs + (wc + j * 16 + r16) * 64 + kk + quad * 8);
#pragma unroll
      for (int i = 0; i < 4; ++i)
#pragma unroll
        for (int j = 0; j < 4; ++j)
          acc[i][j] = __builtin_amdgcn_mfma_f32_16x16x32_bf16(af[i], bfg[j], acc[i][j], 0, 0, 0);
    }
    __syncthreads();
  }

  // D mapping (verified m89/m91): row = quad*4 + reg, col = lane&15
#pragma unroll
  for (int j = 0; j < 4; ++j) {
    const int col = n0 + wc + j * 16 + r16;
    const float bv = BIAS ? bias[col] : 0.0f;
#pragma unroll
    for (int i = 0; i < 4; ++i) {
      const int rowb = m0 + wr + i * 16 + quad * 4;
#pragma unroll
      for (int r = 0; r < 4; ++r) {
        const float v = acc[i][j][r] + bv;
        if constexpr (sizeof(TO) == 2)
          C[(size_t)(rowb + r) * ldc + col] = __float2bfloat16(v);
        else
          C[(size_t)(rowb + r) * ldc + col] = v;
      }
    }
  }
}

// ---------------------------------------------------------------------------
// softmax(k over dh=64) + ctx[bh][d][e] += sum_n sk[n,d]*v[n,e]  via MFMA.
// ---------------------------------------------------------------------------
__global__ __launch_bounds__(256)
void softmax_context(const unsigned short* __restrict__ kv, float* __restrict__ ctx) {
  __shared__ unsigned short skT[64 * 130];
  __shared__ unsigned short vT [64 * 130];

  const int tid   = threadIdx.x;
  const int wave  = tid >> 6;
  const int lane  = tid & 63;
  const int bh    = blockIdx.x >> 4;
  const int slice = blockIdx.x & 15;
  const int b     = bh >> 3, h = bh & 7;

  const int quad = lane >> 4;
  const int r16  = lane & 15;
  const int d0   = wave * 16;

  floatx4 acc[4];
#pragma unroll
  for (int j = 0; j < 4; ++j) acc[j] = (floatx4)0.0f;

  const int rgrp = tid >> 3;
  const int c    = tid & 7;

  for (int ch = 0; ch < 2; ++ch) {
#pragma unroll
    for (int p = 0; p < 4; ++p) {
      const int r = p * 32 + rgrp;
      const size_t rowbase =
          (size_t)(b * NSEQ + slice * 256 + ch * 128 + r) * 1024 + h * 64;
      const uint4 k8 = *(const uint4*)(kv + rowbase + c * 8);
      const uint4 v8 = *(const uint4*)(kv + rowbase + 512 + c * 8);
      const unsigned short* kb = (const unsigned short*)&k8;
      const unsigned short* vb = (const unsigned short*)&v8;

      float kf[8];
#pragma unroll
      for (int j = 0; j < 8; ++j) kf[j] = bf2f(kb[j]);
      float mx = kf[0];
#pragma unroll
      for (int j = 1; j < 8; ++j) mx = fmaxf(mx, kf[j]);
      mx = fmaxf(mx, __shfl_xor(mx, 1, 64));
      mx = fmaxf(mx, __shfl_xor(mx, 2, 64));
      mx = fmaxf(mx, __shfl_xor(mx, 4, 64));
      float e[8]; float s = 0.0f;
#pragma unroll
      for (int j = 0; j < 8; ++j) { e[j] = __expf(kf[j] - mx); s += e[j]; }
      s += __shfl_xor(s, 1, 64);
      s += __shfl_xor(s, 2, 64);
      s += __shfl_xor(s, 4, 64);
      const float inv = 1.0f / s;
#pragma unroll
      for (int j = 0; j < 8; ++j) {
        const int d = c * 8 + j;
        skT[d * 130 + r] = f2bf(e[j] * inv);
        vT [d * 130 + r] = vb[j];
      }
    }
    __syncthreads();

#pragma unroll
    for (int kk = 0; kk < 4; ++kk) {
      const int kof = kk * 32 + quad * 8;
      union { short8 v; unsigned u[4]; } afr;
      {
        const unsigned* q = (const unsigned*)(skT + (d0 + r16) * 130 + kof);
        afr.u[0] = q[0]; afr.u[1] = q[1]; afr.u[2] = q[2]; afr.u[3] = q[3];
      }
#pragma unroll
      for (int j = 0; j < 4; ++j) {
        union { short8 v; unsigned u[4]; } bfr;
        const unsigned* q = (const unsigned*)(vT + (j * 16 + r16) * 130 + kof);
        bfr.u[0] = q[0]; bfr.u[1] = q[1]; bfr.u[2] = q[2]; bfr.u[3] = q[3];
        acc[j] = __builtin_amdgcn_mfma_f32_16x16x32_bf16(afr.v, bfr.v, acc[j], 0, 0, 0);
      }
    }
    __syncthreads();
  }

  float* cg = ctx + (size_t)bh * 4096;
#pragma unroll
  for (int j = 0; j < 4; ++j) {
    const int e = j * 16 + r16;
#pragma unroll
    for (int r = 0; r < 4; ++r) {
      const int d = d0 + quad * 4 + r;
      atomicAdd(cg + d * 64 + e, acc[j][r]);
    }
  }
}

// ---------------------------------------------------------------------------
// wqT[c][c'] = bf16(wq[c'][c])   wq fp32 [512][1024]
// ---------------------------------------------------------------------------
__global__ __launch_bounds__(256)
void transpose_wq(const float* __restrict__ wq, bf16* __restrict__ wqT) {
  __shared__ unsigned short t[64 * 68];
  const int tid = threadIdx.x;
  const int c0  = blockIdx.x * 64;
  const int r0  = blockIdx.y * 64;

#pragma unroll
  for (int l = 0; l < 4; ++l) {
    const int s = l * 256 + tid;
    const int row = s >> 4, col4 = s & 15;
    const float4 v = *(const float4*)(wq + (size_t)(r0 + row) * 1024 + c0 + col4 * 4);
    t[row * 68 + col4 * 4 + 0] = f2bf(v.x);
    t[row * 68 + col4 * 4 + 1] = f2bf(v.y);
    t[row * 68 + col4 * 4 + 2] = f2bf(v.z);
    t[row * 68 + col4 * 4 + 3] = f2bf(v.w);
  }
  __syncthreads();
#pragma unroll
  for (int l = 0; l < 2; ++l) {
    const int s = l * 256 + tid;
    const int cc = s >> 3, g = s & 7;
    union { uint4 u; unsigned short h[8]; } o;
#pragma unroll
    for (int u = 0; u < 8; ++u) o.h[u] = t[(g * 8 + u) * 68 + cc];
    *(uint4*)((unsigned short*)wqT + (size_t)(c0 + cc) * 512 + r0 + g * 8) = o.u;
  }
}

// ---------------------------------------------------------------------------
// M2[b*1024+o][h*64+d] = sum_e w_out[o][h*64+e] * ctx[b,h][d][e]; w_out fp32.
// ---------------------------------------------------------------------------
__global__ __launch_bounds__(256)
void build_m2(const float* __restrict__ w_out, const float* __restrict__ ctx,
              bf16* __restrict__ M2) {
  __shared__ unsigned short wo_s[128 * 68];
  __shared__ __align__(16) float ctx_s[4096];

  const int tid = threadIdx.x;
  const int bh  = blockIdx.y;
  const int b   = bh >> 3, h = bh & 7;
  const int o0  = blockIdx.x * 128;

#pragma unroll
  for (int l = 0; l < 8; ++l) {
    const int s = l * 256 + tid;
    const int row = s >> 4, col4 = s & 15;
    const float4 v = *(const float4*)(w_out + (size_t)(o0 + row) * 512 + h * 64 + col4 * 4);
    wo_s[row * 68 + col4 * 4 + 0] = f2bf(v.x);
    wo_s[row * 68 + col4 * 4 + 1] = f2bf(v.y);
    wo_s[row * 68 + col4 * 4 + 2] = f2bf(v.z);
    wo_s[row * 68 + col4 * 4 + 3] = f2bf(v.w);
  }
  const float4* cg = (const float4*)(ctx + (size_t)bh * 4096);
#pragma unroll
  for (int l = 0; l < 4; ++l) ((float4*)ctx_s)[l * 256 + tid] = cg[l * 256 + tid];
  __syncthreads();

  const int o_loc = tid & 127;
  const int dbase = (tid >> 7) * 32;
  float acc[32];
#pragma unroll
  for (int d = 0; d < 32; ++d) acc[d] = 0.0f;

  for (int e = 0; e < 64; ++e) {
    const float wf = bf2f(wo_s[o_loc * 68 + e]);
#pragma unroll
    for (int d = 0; d < 32; ++d)
      acc[d] += wf * ctx_s[(dbase + d) * 64 + e];
  }

  union { uint4 u[4]; unsigned short h[32]; } o;
#pragma unroll
  for (int d = 0; d < 32; ++d) o.h[d] = f2bf(acc[d]);
  unsigned short* dst = (unsigned short*)M2 + (size_t)(b * 1024 + o0 + o_loc) * 512 + h * 64 + dbase;
#pragma unroll
  for (int i = 0; i < 4; ++i) ((uint4*)dst)[i] = o.u[i];
}

// ---------------------------------------------------------------------------
extern "C" void kernel_launch(void* const* d_in, const int* in_sizes, int n_in,
                              void* d_out, int out_size, void* d_ws, size_t ws_size,
                              hipStream_t stream) {
  const float* x     = (const float*)d_in[0];
  const float* w_qkv = (const float*)d_in[1];
  const float* w_out = (const float*)d_in[2];
  const float* b_out = (const float*)d_in[3];
  float* out = (float*)d_out;

  char* xbuf = (char*)d_in[0];
  char* wbuf = (char*)d_in[1];

  bf16*  xb   = (bf16*)d_out;                        // [0,32 MiB) of d_out
  bf16*  kv   = (bf16*)xbuf;                         // [0,32)
  bf16*  M2   = (bf16*)(xbuf + (size_t)33554432);    // [32,36)
  bf16*  W2   = (bf16*)(xbuf + (size_t)37748736);    // [36,44)
  bf16*  wkvb = (bf16*)(xbuf + (size_t)50331648);    // [48,50)
  bf16*  xblo = (bf16*)xbuf;                         // [0,16) after kv dead
  bf16*  wqT  = (bf16*)(wbuf + 2097152);             // [2,3)
  float* ctx  = (float*)(wbuf + 3145728);            // [3,3.5)

  // 1) xb = bf16(x); x buffer becomes scratch
  convert_x<<<8192, 256, 0, stream>>>(x, xb);
  // 2) wkvb = bf16(w_qkv rows 512..1535)
  convert_x<<<512, 256, 0, stream>>>(w_qkv + (size_t)INNER * DIM, wkvb);

  // 3) kv = xb @ wkvb^T  (M=16384, N=1024, K=1024), grid 1D 1024, mTiles=128
  gemm_bt<bf16, false><<<1024, 256, 0, stream>>>(
      xb, DIM, wkvb, 0, 128, nullptr, kv, 1024, DIM);

  // 4) wbuf bytes [2,6) dead: ctx zero + wqT transpose
  zero_ctx<<<128, 256, 0, stream>>>(ctx);
  transpose_wq<<<dim3(16, 8), 256, 0, stream>>>(w_qkv, wqT);

  // 5) ctx = softmax(k)^T v
  softmax_context<<<512, 256, 0, stream>>>((const unsigned short*)kv, ctx);

  // 6) M2 = w_out folded through ctx
  build_m2<<<dim3(8, 32), 256, 0, stream>>>(w_out, ctx, M2);

  // 7) W2 = M2 @ wqT^T  (M=4096, N=1024, K=512), grid 256, mTiles=32
  gemm_bt<bf16, false><<<256, 256, 0, stream>>>(
      M2, 512, wqT, 0, 32, nullptr, W2, 1024, 512);

  // 8a) out rows 8192..16383 (batches 2,3): reads xb[16,32), writes d_out[32,64)
  gemm_bt<float, true><<<512, 256, 0, stream>>>(
      xb + (size_t)8192 * DIM, DIM, W2 + (size_t)2 * 1048576, (size_t)1048576, 64,
      b_out, out + (size_t)8192 * DIM, DIM, DIM);

  // 8b) relocate xb rows 0..8191 (16 MiB) into xbuf (kv dead)
  copy16<<<4096, 256, 0, stream>>>((const uint4*)xb, (uint4*)xblo);

  // 8c) out rows 0..8191 (batches 0,1) from the copy; writes d_out[0,32)
  gemm_bt<float, true><<<512, 256, 0, stream>>>(
      xblo, DIM, W2, (size_t)1048576, 64,
      b_out, out, DIM, DIM);
}

// Round 9
// 252.333 us; speedup vs baseline: 2.0322x; 1.0726x over previous
//
#include <hip/hip_runtime.h>
#include <hip/hip_bf16.h>

using bf16 = __hip_bfloat16;
typedef __attribute__((ext_vector_type(8))) short short8;
typedef __attribute__((ext_vector_type(4))) float floatx4;

#define NB 4
#define NSEQ 4096
#define DIM 1024
#define INNER 512
#define TOK (NB * NSEQ)   // 16384

// -------------------------- memory plan (no d_ws) ---------------------------
// xbuf = x input (64 MiB, restorable):
//   [0,2)   wkvb bf16 [1024][1024]     (stage 4; xbuf lo dead after stage 2)
//   [2,6)   M2 bf16 [4096][512]        (stage 8)
//   [6,14)  W2 bf16 [4096][1024]       (stage 9)
//   [32,48) xb rows 0..8191            (stage 2: reads xbuf[0,32) - disjoint)
//   [48,64) xb rows 8192..16383        (stage 3 copy from d_out[0,16))
// d_out (64 MiB):
//   [0,16)  xb-hi staging              (stage 1; relocated by stage 3)
//   [0,32)  kv bf16 [16384][1024]      (stage 5 writes, stage 7 reads)
//   [0,64)  final output               (stage 10)
// wbuf = w_qkv input (6 MiB fp32):
//   [0,2)   wq fp32 (pristine, read by transpose)
//   [2,3)   wqT bf16 [1024][512]       (after stage 4 consumed w_kv fp32)
//   [3,3.5) ctx fp32 [32][64][64]

__device__ inline unsigned short f2bf(float x) {
  union { bf16 h; unsigned short u; } c; c.h = __float2bfloat16(x); return c.u;
}
__device__ inline float bf2f(unsigned short u) {
  return __uint_as_float((unsigned)u << 16);
}
__device__ inline void cvt8(const float* __restrict__ src, bf16* dst) {
  const float4 a = ((const float4*)src)[0];
  const float4 b = ((const float4*)src)[1];
  union { uint4 u; bf16 h[8]; } p;
  p.h[0] = __float2bfloat16(a.x); p.h[1] = __float2bfloat16(a.y);
  p.h[2] = __float2bfloat16(a.z); p.h[3] = __float2bfloat16(a.w);
  p.h[4] = __float2bfloat16(b.x); p.h[5] = __float2bfloat16(b.y);
  p.h[6] = __float2bfloat16(b.z); p.h[7] = __float2bfloat16(b.w);
  *(uint4*)dst = p.u;
}

// async global->LDS, 16 B per lane; HW writes lane i at ldsbase + i*16.
__device__ inline void gload_lds16(const bf16* g, bf16* ldsbase) {
  __builtin_amdgcn_global_load_lds(
      (const __attribute__((address_space(1))) void*)g,
      (__attribute__((address_space(3))) void*)ldsbase, 16, 0, 0);
}

// ---------------------------------------------------------------------------
__global__ __launch_bounds__(256)
void convert_x(const float* __restrict__ x, bf16* __restrict__ xb) {
  const size_t i = (size_t)blockIdx.x * 256 + threadIdx.x;
  cvt8(x + i * 8, xb + i * 8);
}

__global__ __launch_bounds__(256)
void copy16(const uint4* __restrict__ src, uint4* __restrict__ dst) {
  const size_t i = (size_t)blockIdx.x * 256 + threadIdx.x;
  dst[i] = src[i];
}

__global__ void zero_ctx(float* __restrict__ ctx) {
  ((float4*)ctx)[blockIdx.x * 256 + threadIdx.x] = make_float4(0.f, 0.f, 0.f, 0.f);
}

// ---------------------------------------------------------------------------
// GEMM: C = A[M,K] @ W[N,K]^T (+bias). 128x128 tile, BK=64, 4 waves,
// 4x4 mfma_f32_16x16x32_bf16. global_load_lds width=16 staging with XOR
// swizzle: lane loads global chunk (lcol^lrow) so element (row,chunk) sits at
// LDS row*64 + ((chunk^(row&7))*8) -> fragment b128 reads hit the 8-access/bank
// floor (was 16-way aliased unswizzled). 1D grid, m = p % mTiles for XCD reuse.
// ---------------------------------------------------------------------------
template <typename TO, bool BIAS>
__global__ __launch_bounds__(256, 4)
void gemm_bt(const bf16* __restrict__ A, int lda,
             const bf16* __restrict__ W, size_t wbatch, int mTiles,
             const float* __restrict__ bias,
             TO* __restrict__ C, int ldc, int K) {
  __shared__ __align__(16) bf16 As[128 * 64];
  __shared__ __align__(16) bf16 Bs[128 * 64];

  const int tid    = threadIdx.x;
  const int p      = blockIdx.x;
  const int m_tile = p % mTiles;
  const int n_tile = p / mTiles;
  const int m0     = m_tile * 128;
  const int n0     = n_tile * 128;
  if (wbatch) W += (size_t)(m_tile >> 5) * wbatch;

  const int wave = tid >> 6;
  const int lane = tid & 63;
  const int wr   = (wave >> 1) * 64;
  const int wc   = (wave & 1) * 64;
  const int quad = lane >> 4;
  const int r16  = lane & 15;
  const int rxor = r16 & 7;
  const int lrow = lane >> 3;       // 0..7 row within segment
  const int lcol = lane & 7;        // LDS slot chunk
  const int gchunk = lcol ^ lrow;   // global chunk this lane fetches

  floatx4 acc[4][4];
#pragma unroll
  for (int i = 0; i < 4; ++i)
#pragma unroll
    for (int j = 0; j < 4; ++j) acc[i][j] = (floatx4)0.0f;

  const int ksteps = K >> 6;
  for (int kt = 0; kt < ksteps; ++kt) {
    const int k0 = kt << 6;
#pragma unroll
    for (int t = 0; t < 4; ++t) {
      const int s   = wave * 4 + t;
      const int row = s * 8 + lrow;
      gload_lds16(A + (size_t)(m0 + row) * lda + k0 + gchunk * 8, As + s * 512);
      gload_lds16(W + (size_t)(n0 + row) * K   + k0 + gchunk * 8, Bs + s * 512);
    }
    __syncthreads();
#pragma unroll
    for (int kk = 0; kk < 64; kk += 32) {
      const int cbase = kk >> 3;    // 0 or 4
      short8 af[4], bfg[4];
#pragma unroll
      for (int i = 0; i < 4; ++i)
        af[i] = *(const short8*)(As + (wr + i * 16 + r16) * 64 + (((quad + cbase) ^ rxor) << 3));
#pragma unroll
      for (int j = 0; j < 4; ++j)
        bfg[j] = *(const short8*)(Bs + (wc + j * 16 + r16) * 64 + (((quad + cbase) ^ rxor) << 3));
#pragma unroll
      for (int i = 0; i < 4; ++i)
#pragma unroll
        for (int j = 0; j < 4; ++j)
          acc[i][j] = __builtin_amdgcn_mfma_f32_16x16x32_bf16(af[i], bfg[j], acc[i][j], 0, 0, 0);
    }
    __syncthreads();
  }

  // D mapping (verified m89/m91): row = quad*4 + reg, col = lane&15
#pragma unroll
  for (int j = 0; j < 4; ++j) {
    const int col = n0 + wc + j * 16 + r16;
    const float bv = BIAS ? bias[col] : 0.0f;
#pragma unroll
    for (int i = 0; i < 4; ++i) {
      const int rowb = m0 + wr + i * 16 + quad * 4;
#pragma unroll
      for (int r = 0; r < 4; ++r) {
        const float v = acc[i][j][r] + bv;
        if constexpr (sizeof(TO) == 2)
          C[(size_t)(rowb + r) * ldc + col] = __float2bfloat16(v);
        else
          C[(size_t)(rowb + r) * ldc + col] = v;
      }
    }
  }
}

// ---------------------------------------------------------------------------
// softmax(k over dh=64) + ctx[bh][d][e] += sum_n sk[n,d]*v[n,e]  via MFMA.
// ---------------------------------------------------------------------------
__global__ __launch_bounds__(256)
void softmax_context(const unsigned short* __restrict__ kv, float* __restrict__ ctx) {
  __shared__ unsigned short skT[64 * 130];
  __shared__ unsigned short vT [64 * 130];

  const int tid   = threadIdx.x;
  const int wave  = tid >> 6;
  const int lane  = tid & 63;
  const int bh    = blockIdx.x >> 4;
  const int slice = blockIdx.x & 15;
  const int b     = bh >> 3, h = bh & 7;

  const int quad = lane >> 4;
  const int r16  = lane & 15;
  const int d0   = wave * 16;

  floatx4 acc[4];
#pragma unroll
  for (int j = 0; j < 4; ++j) acc[j] = (floatx4)0.0f;

  const int rgrp = tid >> 3;
  const int c    = tid & 7;

  for (int ch = 0; ch < 2; ++ch) {
#pragma unroll
    for (int p = 0; p < 4; ++p) {
      const int r = p * 32 + rgrp;
      const size_t rowbase =
          (size_t)(b * NSEQ + slice * 256 + ch * 128 + r) * 1024 + h * 64;
      const uint4 k8 = *(const uint4*)(kv + rowbase + c * 8);
      const uint4 v8 = *(const uint4*)(kv + rowbase + 512 + c * 8);
      const unsigned short* kb = (const unsigned short*)&k8;
      const unsigned short* vb = (const unsigned short*)&v8;

      float kf[8];
#pragma unroll
      for (int j = 0; j < 8; ++j) kf[j] = bf2f(kb[j]);
      float mx = kf[0];
#pragma unroll
      for (int j = 1; j < 8; ++j) mx = fmaxf(mx, kf[j]);
      mx = fmaxf(mx, __shfl_xor(mx, 1, 64));
      mx = fmaxf(mx, __shfl_xor(mx, 2, 64));
      mx = fmaxf(mx, __shfl_xor(mx, 4, 64));
      float e[8]; float s = 0.0f;
#pragma unroll
      for (int j = 0; j < 8; ++j) { e[j] = __expf(kf[j] - mx); s += e[j]; }
      s += __shfl_xor(s, 1, 64);
      s += __shfl_xor(s, 2, 64);
      s += __shfl_xor(s, 4, 64);
      const float inv = 1.0f / s;
#pragma unroll
      for (int j = 0; j < 8; ++j) {
        const int d = c * 8 + j;
        skT[d * 130 + r] = f2bf(e[j] * inv);
        vT [d * 130 + r] = vb[j];
      }
    }
    __syncthreads();

#pragma unroll
    for (int kk = 0; kk < 4; ++kk) {
      const int kof = kk * 32 + quad * 8;
      union { short8 v; unsigned u[4]; } afr;
      {
        const unsigned* q = (const unsigned*)(skT + (d0 + r16) * 130 + kof);
        afr.u[0] = q[0]; afr.u[1] = q[1]; afr.u[2] = q[2]; afr.u[3] = q[3];
      }
#pragma unroll
      for (int j = 0; j < 4; ++j) {
        union { short8 v; unsigned u[4]; } bfr;
        const unsigned* q = (const unsigned*)(vT + (j * 16 + r16) * 130 + kof);
        bfr.u[0] = q[0]; bfr.u[1] = q[1]; bfr.u[2] = q[2]; bfr.u[3] = q[3];
        acc[j] = __builtin_amdgcn_mfma_f32_16x16x32_bf16(afr.v, bfr.v, acc[j], 0, 0, 0);
      }
    }
    __syncthreads();
  }

  float* cg = ctx + (size_t)bh * 4096;
#pragma unroll
  for (int j = 0; j < 4; ++j) {
    const int e = j * 16 + r16;
#pragma unroll
    for (int r = 0; r < 4; ++r) {
      const int d = d0 + quad * 4 + r;
      atomicAdd(cg + d * 64 + e, acc[j][r]);
    }
  }
}

// ---------------------------------------------------------------------------
// wqT[c][c'] = bf16(wq[c'][c])   wq fp32 [512][1024]
// ---------------------------------------------------------------------------
__global__ __launch_bounds__(256)
void transpose_wq(const float* __restrict__ wq, bf16* __restrict__ wqT) {
  __shared__ unsigned short t[64 * 68];
  const int tid = threadIdx.x;
  const int c0  = blockIdx.x * 64;
  const int r0  = blockIdx.y * 64;

#pragma unroll
  for (int l = 0; l < 4; ++l) {
    const int s = l * 256 + tid;
    const int row = s >> 4, col4 = s & 15;
    const float4 v = *(const float4*)(wq + (size_t)(r0 + row) * 1024 + c0 + col4 * 4);
    t[row * 68 + col4 * 4 + 0] = f2bf(v.x);
    t[row * 68 + col4 * 4 + 1] = f2bf(v.y);
    t[row * 68 + col4 * 4 + 2] = f2bf(v.z);
    t[row * 68 + col4 * 4 + 3] = f2bf(v.w);
  }
  __syncthreads();
#pragma unroll
  for (int l = 0; l < 2; ++l) {
    const int s = l * 256 + tid;
    const int cc = s >> 3, g = s & 7;
    union { uint4 u; unsigned short h[8]; } o;
#pragma unroll
    for (int u = 0; u < 8; ++u) o.h[u] = t[(g * 8 + u) * 68 + cc];
    *(uint4*)((unsigned short*)wqT + (size_t)(c0 + cc) * 512 + r0 + g * 8) = o.u;
  }
}

// ---------------------------------------------------------------------------
// M2[b*1024+o][h*64+d] = sum_e w_out[o][h*64+e] * ctx[b,h][d][e]; w_out fp32.
// ---------------------------------------------------------------------------
__global__ __launch_bounds__(256)
void build_m2(const float* __restrict__ w_out, const float* __restrict__ ctx,
              bf16* __restrict__ M2) {
  __shared__ unsigned short wo_s[128 * 68];
  __shared__ __align__(16) float ctx_s[4096];

  const int tid = threadIdx.x;
  const int bh  = blockIdx.y;
  const int b   = bh >> 3, h = bh & 7;
  const int o0  = blockIdx.x * 128;

#pragma unroll
  for (int l = 0; l < 8; ++l) {
    const int s = l * 256 + tid;
    const int row = s >> 4, col4 = s & 15;
    const float4 v = *(const float4*)(w_out + (size_t)(o0 + row) * 512 + h * 64 + col4 * 4);
    wo_s[row * 68 + col4 * 4 + 0] = f2bf(v.x);
    wo_s[row * 68 + col4 * 4 + 1] = f2bf(v.y);
    wo_s[row * 68 + col4 * 4 + 2] = f2bf(v.z);
    wo_s[row * 68 + col4 * 4 + 3] = f2bf(v.w);
  }
  const float4* cg = (const float4*)(ctx + (size_t)bh * 4096);
#pragma unroll
  for (int l = 0; l < 4; ++l) ((float4*)ctx_s)[l * 256 + tid] = cg[l * 256 + tid];
  __syncthreads();

  const int o_loc = tid & 127;
  const int dbase = (tid >> 7) * 32;
  float acc[32];
#pragma unroll
  for (int d = 0; d < 32; ++d) acc[d] = 0.0f;

  for (int e = 0; e < 64; ++e) {
    const float wf = bf2f(wo_s[o_loc * 68 + e]);
#pragma unroll
    for (int d = 0; d < 32; ++d)
      acc[d] += wf * ctx_s[(dbase + d) * 64 + e];
  }

  union { uint4 u[4]; unsigned short h[32]; } o;
#pragma unroll
  for (int d = 0; d < 32; ++d) o.h[d] = f2bf(acc[d]);
  unsigned short* dst = (unsigned short*)M2 + (size_t)(b * 1024 + o0 + o_loc) * 512 + h * 64 + dbase;
#pragma unroll
  for (int i = 0; i < 4; ++i) ((uint4*)dst)[i] = o.u[i];
}

// ---------------------------------------------------------------------------
extern "C" void kernel_launch(void* const* d_in, const int* in_sizes, int n_in,
                              void* d_out, int out_size, void* d_ws, size_t ws_size,
                              hipStream_t stream) {
  const float* x     = (const float*)d_in[0];
  const float* w_qkv = (const float*)d_in[1];
  const float* w_out = (const float*)d_in[2];
  const float* b_out = (const float*)d_in[3];
  float* out = (float*)d_out;

  char* xbuf = (char*)d_in[0];
  char* wbuf = (char*)d_in[1];

  bf16*  wkvb = (bf16*)xbuf;                         // [0,2)
  bf16*  M2   = (bf16*)(xbuf + (size_t)2097152);     // [2,6)
  bf16*  W2   = (bf16*)(xbuf + (size_t)6291456);     // [6,14)
  bf16*  xb   = (bf16*)(xbuf + (size_t)33554432);    // [32,64): full xb
  bf16*  xbhi_stage = (bf16*)d_out;                  // d_out[0,16) temp
  bf16*  kv   = (bf16*)d_out;                        // d_out[0,32)
  bf16*  wqT  = (bf16*)(wbuf + 2097152);             // [2,3)
  float* ctx  = (float*)(wbuf + 3145728);            // [3,3.5)

  // 1) xb-hi = bf16(x rows 8192..16383) -> d_out[0,16)   (reads xbuf[32,64))
  convert_x<<<4096, 256, 0, stream>>>(x + (size_t)8192 * DIM, xbhi_stage);
  // 2) xb-lo = bf16(x rows 0..8191) -> xbuf[32,48)       (reads xbuf[0,32) - disjoint)
  convert_x<<<4096, 256, 0, stream>>>(x, xb);
  // 3) relocate xb-hi -> xbuf[48,64)  (x rows 12288+ dead after 1)
  copy16<<<4096, 256, 0, stream>>>((const uint4*)xbhi_stage,
                                   (uint4*)(xb + (size_t)8192 * DIM));
  // 4) wkvb = bf16(w_qkv rows 512..1535) -> xbuf[0,2)  (xbuf lo dead after 2)
  convert_x<<<512, 256, 0, stream>>>(w_qkv + (size_t)INNER * DIM, wkvb);

  // 5) kv = xb @ wkvb^T -> d_out[0,32). grid 1024, mTiles=128.
  gemm_bt<bf16, false><<<1024, 256, 0, stream>>>(
      xb, DIM, wkvb, 0, 128, nullptr, kv, 1024, DIM);

  // 6) ctx zero + wqT transpose (w_kv fp32 region of wbuf dead after 4)
  zero_ctx<<<128, 256, 0, stream>>>(ctx);
  transpose_wq<<<dim3(16, 8), 256, 0, stream>>>(w_qkv, wqT);

  // 7) ctx = softmax(k)^T v
  softmax_context<<<512, 256, 0, stream>>>((const unsigned short*)kv, ctx);

  // 8) M2 = w_out folded through ctx -> xbuf[2,6)
  build_m2<<<dim3(8, 32), 256, 0, stream>>>(w_out, ctx, M2);

  // 9) W2 = M2 @ wqT^T -> xbuf[6,14). grid 256, mTiles=32.
  gemm_bt<bf16, false><<<256, 256, 0, stream>>>(
      M2, 512, wqT, 0, 32, nullptr, W2, 1024, 512);

  // 10) out = xb @ W2[b]^T + b_out -> all of d_out (kv dead). grid 1024.
  gemm_bt<float, true><<<1024, 256, 0, stream>>>(
      xb, DIM, W2, (size_t)1048576, 128, b_out, out, DIM, DIM);
}